// Round 1
// baseline (68.397 us; speedup 1.0000x reference)
//
#include <hip/hip_runtime.h>

#define TPB 256

constexpr int CODE_LEN = 1024;
constexpr int INFO_LEN = 512;
constexpr int BATCH    = 2048;
constexpr int ITERS    = 5;
constexpr int NST      = 10;
#define CLIPV 15.0f

// Word-index swizzle: spreads small-stride stage accesses across banks.
// Affects only bits 1..4 (keeps float2 pairs contiguous & 8B-aligned, and
// (w>>5) is constant within each 32-word group so pairs never straddle).
__device__ __forceinline__ int swz(int w) {
    return w ^ ((((w >> 5) * 9) & 15) << 1);
}

// f(a,b) = sign(a)*sign(b)*min(|a|,|b|)  (sign-of-zero differences are harmless)
__device__ __forceinline__ float fop(float a, float b) {
    float m = fminf(fabsf(a), fabsf(b));
    unsigned s = (__float_as_uint(a) ^ __float_as_uint(b)) & 0x80000000u;
    return __uint_as_float(__float_as_uint(m) | s);
}

__device__ __forceinline__ float clipf(float x) {
    return fminf(fmaxf(x, -CLIPV), CLIPV);
}

__global__ __launch_bounds__(TPB) void polar_bp(const float* __restrict__ rx,
                                                const int* __restrict__ info,
                                                float* __restrict__ out) {
    // S[k] holds stage-(k+1) values; meaning alternates left<->right per pass.
    // S[9] = left[10] = rx, never overwritten (right stage 9 output is unused).
    __shared__ float S[NST][CODE_LEN];
    __shared__ float FR[CODE_LEN];   // right[0] = (1-mask)*CLIP, constant
    __shared__ int   RK[CODE_LEN];   // position -> output rank (or -1)

    const int t = threadIdx.x;
    const int b = blockIdx.x;
    const float* rxb = rx + (size_t)b * CODE_LEN;

    // ---- init: rx -> S[9]; left[1..9]=0 -> S[0..8]; frozen + rank tables ----
#pragma unroll
    for (int j = 0; j < 2; ++j) {
        int fi = t + TPB * j;        // float2 index 0..511
        int w  = 2 * fi;
        int sw = swz(w);
        float2 v = ((const float2*)rxb)[fi];
        *(float2*)&S[NST - 1][sw] = v;
        float2 z = make_float2(0.f, 0.f);
#pragma unroll
        for (int k = 0; k < NST - 1; ++k)
            *(float2*)&S[k][sw] = z;
        *(float2*)&FR[sw] = make_float2(CLIPV, CLIPV);
        RK[sw] = -1;
        RK[sw + 1] = -1;
    }
    __syncthreads();
#pragma unroll
    for (int j = 0; j < 2; ++j) {
        int k = t + TPB * j;         // 512 info indices
        int idx = info[k];
        int sw = swz(idx);
        FR[sw] = 0.f;
        RK[sw] = k;
    }
    __syncthreads();

    for (int it = 0; it < ITERS; ++it) {
        // ================= RIGHT pass: s = 0..8 (right[9+..] unused) ========
        {   // s = 0: cur = frozen (FR), l = left[1] = S[0]; write right[1]->S[0]
            int base = 4 * t;
            int p0 = swz(base), p1 = swz(base + 2);
            float2 r0 = *(const float2*)&FR[p0];
            float2 r1 = *(const float2*)&FR[p1];
            float2 l0 = *(const float2*)&S[0][p0];
            float2 l1 = *(const float2*)&S[0][p1];
            float2 n0, n1;
            n0.x = clipf(fop(r0.x, l0.y + r0.y));
            n0.y = clipf(fop(r0.x, l0.x) + r0.y);
            n1.x = clipf(fop(r1.x, l1.y + r1.y));
            n1.y = clipf(fop(r1.x, l1.x) + r1.y);
            *(float2*)&S[0][p0] = n0;
            *(float2*)&S[0][p1] = n1;
        }
        __syncthreads();
#pragma unroll
        for (int s = 1; s <= 8; ++s) {
            // cur = right[s] = S[s-1]; l = left[s+1] = S[s]; write right[s+1]->S[s]
            int st = 1 << s;
            int q0 = 2 * t;
            int up = ((q0 >> s) << (s + 1)) | (q0 & (st - 1));
            int su = swz(up), sl = swz(up + st);
            float2 ru = *(const float2*)&S[s - 1][su];
            float2 rl = *(const float2*)&S[s - 1][sl];
            float2 lu = *(const float2*)&S[s][su];
            float2 ll = *(const float2*)&S[s][sl];
            float2 nu, nl;
            nu.x = clipf(fop(ru.x, ll.x + rl.x));
            nu.y = clipf(fop(ru.y, ll.y + rl.y));
            nl.x = clipf(fop(ru.x, lu.x) + rl.x);
            nl.y = clipf(fop(ru.y, lu.y) + rl.y);
            *(float2*)&S[s][su] = nu;
            *(float2*)&S[s][sl] = nl;
            __syncthreads();
        }
        // ================= LEFT pass: s = 9..1 ==============================
#pragma unroll
        for (int s = 9; s >= 1; --s) {
            // cur = left[s+1] = S[s]; r = right[s] = S[s-1]; write left[s]->S[s-1]
            int st = 1 << s;
            int q0 = 2 * t;
            int up = ((q0 >> s) << (s + 1)) | (q0 & (st - 1));
            int su = swz(up), sl = swz(up + st);
            float2 lu = *(const float2*)&S[s][su];
            float2 ll = *(const float2*)&S[s][sl];
            float2 ru = *(const float2*)&S[s - 1][su];
            float2 rl = *(const float2*)&S[s - 1][sl];
            float2 nu, nl;
            nu.x = clipf(fop(lu.x, ll.x + rl.x));
            nu.y = clipf(fop(lu.y, ll.y + rl.y));
            nl.x = clipf(fop(ru.x, lu.x) + ll.x);
            nl.y = clipf(fop(ru.y, lu.y) + ll.y);
            *(float2*)&S[s - 1][su] = nu;
            *(float2*)&S[s - 1][sl] = nl;
            __syncthreads();
        }
        {   // s = 0: cur = left[1] = S[0]; r = frozen; emit left[0][info]
            int base = 4 * t;
            int p0 = swz(base), p1 = swz(base + 2);
            float2 c0 = *(const float2*)&S[0][p0];
            float2 c1 = *(const float2*)&S[0][p1];
            float2 f0 = *(const float2*)&FR[p0];
            float2 f1 = *(const float2*)&FR[p1];
            float v0 = clipf(fop(c0.x, c0.y + f0.y));
            float v1 = clipf(fop(f0.x, c0.x) + c0.y);
            float v2 = clipf(fop(c1.x, c1.y + f1.y));
            float v3 = clipf(fop(f1.x, c1.x) + c1.y);
            int r0 = RK[p0], r1 = RK[p0 + 1], r2 = RK[p1], r3 = RK[p1 + 1];
            float* ob = out + ((size_t)it * BATCH + b) * INFO_LEN;
            if (r0 >= 0) ob[r0] = v0;
            if (r1 >= 0) ob[r1] = v1;
            if (r2 >= 0) ob[r2] = v2;
            if (r3 >= 0) ob[r3] = v3;
            if (it == ITERS - 1) {
                float* ob2 = out + ((size_t)ITERS * BATCH + b) * INFO_LEN;
                if (r0 >= 0) ob2[r0] = v0;
                if (r1 >= 0) ob2[r1] = v1;
                if (r2 >= 0) ob2[r2] = v2;
                if (r3 >= 0) ob2[r3] = v3;
            }
        }
        __syncthreads();
    }
}

extern "C" void kernel_launch(void* const* d_in, const int* in_sizes, int n_in,
                              void* d_out, int out_size, void* d_ws, size_t ws_size,
                              hipStream_t stream) {
    const float* rx   = (const float*)d_in[0];
    const int*   info = (const int*)d_in[1];
    float*       outp = (float*)d_out;
    polar_bp<<<dim3(BATCH), dim3(TPB), 0, stream>>>(rx, info, outp);
}